// Round 5
// baseline (266.032 us; speedup 1.0000x reference)
//
#include <hip/hip_runtime.h>
#include <hip/hip_bf16.h>

typedef __hip_bfloat16 bf16;
typedef unsigned short u16;
typedef __attribute__((ext_vector_type(8))) short bf16x8;     // MFMA A/B frag: 8 bf16 = 4 VGPRs
typedef __attribute__((ext_vector_type(4))) float f32x4;      // MFMA C/D frag
typedef __attribute__((ext_vector_type(8))) unsigned short u16x8;

#define KD 1024
#define HD 1024
#define BSZ 8192
#define BM 128
#define BN 64
#define BK 32

__device__ __forceinline__ u16 f2b(float f) {
    return __builtin_bit_cast(u16, __float2bfloat16(f));
}

// ---- async global->LDS, 16B per lane, wave-uniform LDS base + lane*16 ----
__device__ __forceinline__ void gload16(const void* g, void* smem, int lds_byte_off) {
    __builtin_amdgcn_global_load_lds(
        (const __attribute__((address_space(1))) void*)g,
        (__attribute__((address_space(3))) void*)((char*)smem + lds_byte_off),
        16, 0, 0);
}

__device__ __forceinline__ bf16x8 packfrag(float4 a, float4 b) {
    bf16x8 r;
    r[0] = (short)f2b(a.x); r[1] = (short)f2b(a.y);
    r[2] = (short)f2b(a.z); r[3] = (short)f2b(a.w);
    r[4] = (short)f2b(b.x); r[5] = (short)f2b(b.y);
    r[6] = (short)f2b(b.z); r[7] = (short)f2b(b.w);
    return r;
}

// ---------------------------------------------------------------------------
// Kernel 1: transpose+cast weights [g][k][n] f32 -> wt[g][n][k] bf16.
// LDS-tiled, coalesced reads AND writes (round-3 version; no swizzle —
// round-4 evidence showed bank swizzles don't move SQ_LDS_BANK_CONFLICT).
// ---------------------------------------------------------------------------
__global__ __launch_bounds__(256) void transpose_w(
    const float* __restrict__ wx, const float* __restrict__ wh, u16* __restrict__ wt)
{
    __shared__ u16 tile[64][65];   // +1 pad breaks bank collisions
    const int g = blockIdx.z;
    const float* src = (g < 3) ? (wx + (size_t)g * KD * HD) : (wh + (size_t)(g - 3) * KD * HD);
    u16* dst = wt + (size_t)g * KD * HD;
    const int r0 = blockIdx.y * 64;   // k rows in src
    const int c0 = blockIdx.x * 64;   // n cols in src
    const int t = threadIdx.x;

    #pragma unroll
    for (int r = 0; r < 2; r++) {
        int idx = r * 256 + t;
        int row = idx >> 3, cc = idx & 7;
        const float* p = src + (size_t)(r0 + row) * HD + c0 + cc * 8;
        #pragma unroll
        for (int e = 0; e < 8; e++) tile[row][cc * 8 + e] = f2b(p[e]);
    }
    __syncthreads();
    #pragma unroll
    for (int r = 0; r < 2; r++) {
        int idx = r * 256 + t;
        int nrow = idx >> 3, kc = idx & 7;
        u16x8 v;
        #pragma unroll
        for (int e = 0; e < 8; e++) v[e] = tile[kc * 8 + e][nrow];
        *(u16x8*)(dst + (size_t)(c0 + nrow) * KD + r0 + kc * 8) = v;
    }
}

// ---------------------------------------------------------------------------
// Kernel 2: fused GRU cell, 16x16x32 MFMA (round-3 structure, best so far).
// NEW: x/h staged as raw f32 via global_load_lds (no separate convert pass);
// f32->bf16 cast happens in-register while building A-fragments (VALU pipe
// has ~75% headroom). A-tile 16B chunks are XOR-permuted within each 128B
// row at staging time so fragment reads spread across banks.
// LDS bytes: fx [0,16384) fh [16384,32768) w [32768 + g*4096)  = 56 KiB.
// 4 acc sets: r(shared x+h), z(shared), nx, nh.
// ---------------------------------------------------------------------------
__global__ __launch_bounds__(256, 2) void gru_fused(
    const float* __restrict__ xf, const float* __restrict__ hf,
    const u16* __restrict__ wt,
    const float* __restrict__ bxf, const float* __restrict__ bhf,
    float* __restrict__ outf)
{
    __shared__ __align__(16) char smem[57344];
    float* fx = (float*)smem;                 // [128][32] f32, chunks swizzled
    float* fh = (float*)(smem + 16384);
    u16*   wl = (u16*)(smem + 32768);         // [6][64][32] bf16

    const int t    = threadIdx.x;
    const int lane = t & 63;
    const int w    = t >> 6;
    const int wm   = w >> 1, wn = w & 1;
    const int quad = lane >> 4;
    const int c16  = lane & 15;
    // XCD swizzle: lin%8 = XCD; 2 n-blocks per XCD keep 1.57 MB weights L2-hot
    const int lin  = blockIdx.x;
    const int nblk = (lin & 7) * 2 + ((lin >> 3) & 1);
    const int mblk = lin >> 4;
    const int m0   = mblk * BM;
    const int n0   = nblk * BN;

    // ---- staging source pointers ----
    // x/h: thread t fills LDS chunk t (+256/round); LDS pos (row,pc) reads
    // global chunk pc ^ (row&7). row = 32r + (t>>3), so the XOR term is
    // r-invariant: csrc = (t&7) ^ ((t>>3)&7).
    const int tq = t >> 3, tc = t & 7;
    const int csrc = tc ^ (tq & 7);
    const float* gx = xf + (size_t)(m0 + tq) * KD + csrc * 4;
    const float* gh = hf + (size_t)(m0 + tq) * KD + csrc * 4;
    const u16*   gw = wt + (size_t)(n0 + (t >> 2)) * KD + (t & 3) * 8;
    const int ldsl = w * 1024;   // wave-uniform byte base (lane adds *16)

    f32x4 acc[4][4][2];
    #pragma unroll
    for (int a = 0; a < 4; a++)
        #pragma unroll
        for (int i = 0; i < 4; i++)
            #pragma unroll
            for (int j = 0; j < 2; j++)
                acc[a][i][j] = (f32x4){0.f, 0.f, 0.f, 0.f};

    // ---- per-lane fragment offsets (precomputed, swizzle folded in) ----
    int iA0[4], iA1[4];
    #pragma unroll
    for (int i = 0; i < 4; i++) {
        int ml = wm * 64 + i * 16 + c16;
        int s  = ml & 7;
        iA0[i] = ml * 32 + ((2 * quad)     ^ s) * 4;
        iA1[i] = ml * 32 + ((2 * quad + 1) ^ s) * 4;
    }
    int iW[2];
    #pragma unroll
    for (int j = 0; j < 2; j++) {
        int nl = wn * 32 + j * 16 + c16;
        iW[j] = nl * 32 + quad * 8;
    }

    for (int k0 = 0; k0 < KD; k0 += BK) {
        #pragma unroll
        for (int r = 0; r < 4; r++)
            gload16(gx + (size_t)(32 * r) * KD, smem, r * 4096 + ldsl);
        #pragma unroll
        for (int r = 0; r < 4; r++)
            gload16(gh + (size_t)(32 * r) * KD, smem, 16384 + r * 4096 + ldsl);
        #pragma unroll
        for (int g = 0; g < 6; g++)
            gload16(gw + (size_t)g * KD * HD, smem, 32768 + g * 4096 + ldsl);
        __syncthreads();
        gx += BK; gh += BK; gw += BK;

        bf16x8 ax[4], ah[4];
        #pragma unroll
        for (int i = 0; i < 4; i++) {
            float4 u0 = *(const float4*)&fx[iA0[i]];
            float4 u1 = *(const float4*)&fx[iA1[i]];
            float4 v0 = *(const float4*)&fh[iA0[i]];
            float4 v1 = *(const float4*)&fh[iA1[i]];
            ax[i] = packfrag(u0, u1);
            ah[i] = packfrag(v0, v1);
        }
        #pragma unroll
        for (int p = 0; p < 3; p++) {        // gates r, z, n
            bf16x8 bwx[2], bwh[2];
            #pragma unroll
            for (int j = 0; j < 2; j++) {
                bwx[j] = *(const bf16x8*)&wl[p * 2048       + iW[j]];
                bwh[j] = *(const bf16x8*)&wl[(p + 3) * 2048 + iW[j]];
            }
            #pragma unroll
            for (int i = 0; i < 4; i++)
                #pragma unroll
                for (int j = 0; j < 2; j++) {
                    if (p < 2) {
                        acc[p][i][j] = __builtin_amdgcn_mfma_f32_16x16x32_bf16(ax[i], bwx[j], acc[p][i][j], 0, 0, 0);
                        acc[p][i][j] = __builtin_amdgcn_mfma_f32_16x16x32_bf16(ah[i], bwh[j], acc[p][i][j], 0, 0, 0);
                    } else {
                        acc[2][i][j] = __builtin_amdgcn_mfma_f32_16x16x32_bf16(ax[i], bwx[j], acc[2][i][j], 0, 0, 0);
                        acc[3][i][j] = __builtin_amdgcn_mfma_f32_16x16x32_bf16(ah[i], bwh[j], acc[3][i][j], 0, 0, 0);
                    }
                }
        }
        __syncthreads();
    }

    // ---- epilogue: C/D layout col=lane&15, row=quad*4+reg ----
    float bR[2], bZ[2], bXN[2], bHN[2];
    #pragma unroll
    for (int j = 0; j < 2; j++) {
        int col = n0 + wn * 32 + j * 16 + c16;
        bR[j]  = bxf[col]          + bhf[col];
        bZ[j]  = bxf[HD + col]     + bhf[HD + col];
        bXN[j] = bxf[2 * HD + col];
        bHN[j] = bhf[2 * HD + col];
    }
    #pragma unroll
    for (int i = 0; i < 4; i++)
        #pragma unroll
        for (int j = 0; j < 2; j++) {
            int col = n0 + wn * 32 + j * 16 + c16;
            #pragma unroll
            for (int r = 0; r < 4; r++) {
                int row = m0 + wm * 64 + i * 16 + quad * 4 + r;
                size_t idx = (size_t)row * HD + col;
                float vr = acc[0][i][j][r] + bR[j];
                vr = 1.f / (1.f + __expf(-vr));
                float vz = acc[1][i][j][r] + bZ[j];
                vz = 1.f / (1.f + __expf(-vz));
                float vn = (acc[2][i][j][r] + bXN[j]) + vr * (acc[3][i][j][r] + bHN[j]);
                float e2 = __expf(2.f * vn);
                vn = 1.f - 2.f / (e2 + 1.f);
                outf[idx] = (1.f - vz) * vn + vz * hf[idx];
            }
        }
}

extern "C" void kernel_launch(void* const* d_in, const int* in_sizes, int n_in,
                              void* d_out, int out_size, void* d_ws, size_t ws_size,
                              hipStream_t stream) {
    const float* x   = (const float*)d_in[0];
    const float* hid = (const float*)d_in[1];
    const float* wx  = (const float*)d_in[2];
    const float* wh  = (const float*)d_in[3];
    const float* bx  = (const float*)d_in[4];
    const float* bh  = (const float*)d_in[5];
    float* out = (float*)d_out;

    u16* wt = (u16*)d_ws;   // 12.6 MB transposed bf16 weights

    dim3 tgrid(HD / 64, KD / 64, 6);
    transpose_w<<<tgrid, 256, 0, stream>>>(wx, wh, wt);
    gru_fused<<<1024, 256, 0, stream>>>(x, hid, wt, bx, bh, out);
}